// Round 4
// baseline (116.085 us; speedup 1.0000x reference)
//
#include <hip/hip_runtime.h>

// Problem constants: B=16, C=3, H=W=512.
// priority(b,y,x) = min(eye+mouth, 1), eye = clip(1 - sqrt(min d2 over pts36..47)/15, 0, 1),
// mouth same over pts 48..67.  weight = 1 + 299*priority.  out = mean(|pred-target|*weight).
//
// Landmark culling: each block covers a 2-row band of one batch image. Only
// landmarks with |cy - row| < 15 can contribute (else clip() is exactly 0),
// so we compact the ~0-3 relevant landmarks into LDS lists and the per-pixel
// distance loop runs over those instead of all 32. Bit-exact: fminf over a
// reordered subset + clip matches the full min whenever the full min matters.

constexpr int   kW        = 512;
constexpr int   kG        = 512 * 512 / 4;  // float4 groups per plane = 65536
constexpr int   kThreads  = 256;
constexpr int   kBlocksX  = kG / kThreads;  // 256 blocks per batch
constexpr int   kBlocks   = kBlocksX * 16;  // 4096 total
constexpr float kInvR     = 1.0f / 15.0f;
constexpr float kInvN     = 1.0f / (16.0f * 3.0f * 512.0f * 512.0f);

__device__ __forceinline__ float clamp01(float v) {
    return fminf(fmaxf(v, 0.0f), 1.0f);
}

__global__ __launch_bounds__(kThreads) void eml_main(
        const float* __restrict__ pred,
        const float* __restrict__ target,
        const int*   __restrict__ lm,      // (16, 68, 2) int32
        float*       __restrict__ partial) // kBlocks floats
{
    __shared__ float s_ex[12], s_ey[12];   // culled eye landmarks
    __shared__ float s_mx[20], s_my[20];   // culled mouth landmarks
    __shared__ int   s_ne, s_nm;

    const int b   = blockIdx.y;
    const int tid = threadIdx.x;
    const int g   = blockIdx.x * kThreads + tid;  // float4-group index in plane
    const int row0 = (blockIdx.x * kThreads) >> 7; // first of the 2 rows this block covers

    if (tid == 0) { s_ne = 0; s_nm = 0; }
    __syncthreads();

    if (tid < 32) {
        const int j  = 36 + tid;                  // points 36..67
        int xi = lm[b * 136 + j * 2 + 0];
        int yi = lm[b * 136 + j * 2 + 1];
        xi = min(max(xi, 0), kW - 1);
        yi = min(max(yi, 0), kW - 1);
        // keep iff landmark can be < 15 px from some row in {row0, row0+1}
        // (conservative by 1 row on each side; extra rows contribute exactly 0)
        if (yi >= row0 - 15 && yi <= row0 + 16) {
            if (tid < 12) {
                const int i = atomicAdd(&s_ne, 1);
                s_ex[i] = (float)xi; s_ey[i] = (float)yi;
            } else {
                const int i = atomicAdd(&s_nm, 1);
                s_mx[i] = (float)xi; s_my[i] = (float)yi;
            }
        }
    }
    __syncthreads();

    const float4* __restrict__ pred4 = (const float4*)pred   + (size_t)b * 3 * kG;
    const float4* __restrict__ tgt4  = (const float4*)target + (size_t)b * 3 * kG;

    // ---- issue ALL global loads first; latency hides behind weight compute
    const float4 p0 = pred4[0 * kG + g];
    const float4 p1 = pred4[1 * kG + g];
    const float4 p2 = pred4[2 * kG + g];
    const float4 t0 = tgt4[0 * kG + g];
    const float4 t1 = tgt4[1 * kG + g];
    const float4 t2 = tgt4[2 * kG + g];

    const int ne = s_ne, nm = s_nm;

    float w0 = 1.0f, w1 = 1.0f, w2 = 1.0f, w3 = 1.0f;
    if ((ne | nm) != 0) {                         // wave-uniform branch
        const float y  = (float)(g >> 7);
        const float x0 = (float)((g & 127) << 2);
        const float x1 = x0 + 1.0f, x2 = x0 + 2.0f, x3 = x0 + 3.0f;

        float de0 = 1e30f, de1 = 1e30f, de2 = 1e30f, de3 = 1e30f;
        float dm0 = 1e30f, dm1 = 1e30f, dm2 = 1e30f, dm3 = 1e30f;

        for (int i = 0; i < ne; ++i) {
            const float dy  = y - s_ey[i];
            const float dy2 = dy * dy;
            float dx;
            dx = x0 - s_ex[i]; de0 = fminf(de0, fmaf(dx, dx, dy2));
            dx = x1 - s_ex[i]; de1 = fminf(de1, fmaf(dx, dx, dy2));
            dx = x2 - s_ex[i]; de2 = fminf(de2, fmaf(dx, dx, dy2));
            dx = x3 - s_ex[i]; de3 = fminf(de3, fmaf(dx, dx, dy2));
        }
        for (int i = 0; i < nm; ++i) {
            const float dy  = y - s_my[i];
            const float dy2 = dy * dy;
            float dx;
            dx = x0 - s_mx[i]; dm0 = fminf(dm0, fmaf(dx, dx, dy2));
            dx = x1 - s_mx[i]; dm1 = fminf(dm1, fmaf(dx, dx, dy2));
            dx = x2 - s_mx[i]; dm2 = fminf(dm2, fmaf(dx, dx, dy2));
            dx = x3 - s_mx[i]; dm3 = fminf(dm3, fmaf(dx, dx, dy2));
        }

        const float e0 = clamp01(1.0f - sqrtf(de0) * kInvR);
        const float e1 = clamp01(1.0f - sqrtf(de1) * kInvR);
        const float e2 = clamp01(1.0f - sqrtf(de2) * kInvR);
        const float e3 = clamp01(1.0f - sqrtf(de3) * kInvR);
        const float m0 = clamp01(1.0f - sqrtf(dm0) * kInvR);
        const float m1 = clamp01(1.0f - sqrtf(dm1) * kInvR);
        const float m2 = clamp01(1.0f - sqrtf(dm2) * kInvR);
        const float m3 = clamp01(1.0f - sqrtf(dm3) * kInvR);

        w0 = fmaf(299.0f, fminf(e0 + m0, 1.0f), 1.0f);
        w1 = fmaf(299.0f, fminf(e1 + m1, 1.0f), 1.0f);
        w2 = fmaf(299.0f, fminf(e2 + m2, 1.0f), 1.0f);
        w3 = fmaf(299.0f, fminf(e3 + m3, 1.0f), 1.0f);
    }

    // ---- consume loads (2 independent accumulator chains, merged at end)
    float accA = 0.0f, accB = 0.0f;
    accA = fmaf(fabsf(p0.x - t0.x), w0, accA);
    accB = fmaf(fabsf(p0.y - t0.y), w1, accB);
    accA = fmaf(fabsf(p0.z - t0.z), w2, accA);
    accB = fmaf(fabsf(p0.w - t0.w), w3, accB);
    accA = fmaf(fabsf(p1.x - t1.x), w0, accA);
    accB = fmaf(fabsf(p1.y - t1.y), w1, accB);
    accA = fmaf(fabsf(p1.z - t1.z), w2, accA);
    accB = fmaf(fabsf(p1.w - t1.w), w3, accB);
    accA = fmaf(fabsf(p2.x - t2.x), w0, accA);
    accB = fmaf(fabsf(p2.y - t2.y), w1, accB);
    accA = fmaf(fabsf(p2.z - t2.z), w2, accA);
    accB = fmaf(fabsf(p2.w - t2.w), w3, accB);
    float acc = accA + accB;

    // wave (64-lane) shuffle reduction
#pragma unroll
    for (int off = 32; off > 0; off >>= 1)
        acc += __shfl_down(acc, off, 64);

    __shared__ float s_wsum[4];
    const int lane = tid & 63;
    const int wid  = tid >> 6;
    if (lane == 0) s_wsum[wid] = acc;
    __syncthreads();
    if (tid == 0)
        partial[b * kBlocksX + blockIdx.x] = s_wsum[0] + s_wsum[1] + s_wsum[2] + s_wsum[3];
}

__global__ __launch_bounds__(256) void eml_finish(
        const float* __restrict__ partial,   // kBlocks = 4096 floats
        float*       __restrict__ out)
{
    const int tid = threadIdx.x;
    float v = 0.0f;
#pragma unroll
    for (int k = 0; k < kBlocks / 256; ++k)      // 16 strided reads
        v += partial[tid + k * 256];
#pragma unroll
    for (int off = 32; off > 0; off >>= 1)
        v += __shfl_down(v, off, 64);

    __shared__ float s_wsum[4];
    if ((tid & 63) == 0) s_wsum[tid >> 6] = v;
    __syncthreads();
    if (tid == 0)
        out[0] = (s_wsum[0] + s_wsum[1] + s_wsum[2] + s_wsum[3]) * kInvN;
}

extern "C" void kernel_launch(void* const* d_in, const int* in_sizes, int n_in,
                              void* d_out, int out_size, void* d_ws, size_t ws_size,
                              hipStream_t stream) {
    const float* pred   = (const float*)d_in[0];
    const float* target = (const float*)d_in[1];
    const int*   lm     = (const int*)d_in[2];
    float* out     = (float*)d_out;
    float* partial = (float*)d_ws;               // 16 KiB

    dim3 grid(kBlocksX, 16);
    eml_main<<<grid, kThreads, 0, stream>>>(pred, target, lm, partial);
    eml_finish<<<1, 256, 0, stream>>>(partial, out);
}